// Round 2
// baseline (9556.588 us; speedup 1.0000x reference)
//
#include <hip/hip_runtime.h>
#include <math.h>

// Problem dims
#define BB 32
#define NN 32
#define EE 256
#define HH 1500
#define G4 6000      // 4*HH
#define QIN 512
#define Q1O 600
#define QO 300
#define EV1 1000
#define EV2 100
#define EV3 10
#define PP 496       // N*(N-1)/2
#define ROWS (BB*PP) // 15872
#define KS2 8        // lstm k-split
#define KCH2 188     // ceil(1500/8)

__device__ __forceinline__ float sigm(float x) { return 1.f / (1.f + expf(-x)); }

// ---------------- init helpers ----------------
__global__ void k_zero(float* a, int n) {
    int i = blockIdx.x * 256 + threadIdx.x;
    if (i < n) a[i] = 0.f;
}

__global__ void k_iijj(int* iijj) {
    int p = threadIdx.x;
    if (p >= PP) return;
    int i = 0, p0 = 0;
    while (p >= p0 + (NN - 1 - i)) { p0 += NN - 1 - i; i++; }
    iijj[p] = i;
    iijj[PP + p] = i + 1 + (p - p0);
}

// q1 effective bias: q1_b[o] + sum over odd k of q1_w[o][k]  (PE at pos 0)
__global__ void k_q1beff(const float* q1w, const float* q1b, float* beff) {
    int o = blockIdx.x * 256 + threadIdx.x;
    if (o >= Q1O) return;
    float a = q1b[o];
    for (int k = 1; k < QIN; k += 2) a += q1w[o * QIN + k];
    beff[o] = a;
}

__global__ void k_addb(const float* a, const float* b, float* c, int n) {
    int i = blockIdx.x * 256 + threadIdx.x;
    if (i < n) c[i] = a[i] + b[i];
}

// ---------------- transpose (sub-range of columns) ----------------
// src[R][C], take columns [c0, c0+csub) -> dst[csub][R]
__global__ void k_transpose(const float* __restrict__ src, float* __restrict__ dst,
                            int R, int C, int c0, int csub) {
    __shared__ float tile[32][33];
    int cb = blockIdx.x * 32, rb = blockIdx.y * 32;
    for (int dy = threadIdx.y; dy < 32; dy += 8) {
        int r = rb + dy, c = cb + threadIdx.x;
        if (r < R && c < csub) tile[dy][threadIdx.x] = src[(size_t)r * C + c0 + c];
    }
    __syncthreads();
    for (int dy = threadIdx.y; dy < 32; dy += 8) {
        int c = cb + dy, r = rb + threadIdx.x;
        if (c < csub && r < R) dst[(size_t)c * R + r] = tile[threadIdx.x][dy];
    }
}

// ---------------- pack w_hh -> wp[k/4][6000] of float4 (w^T, k-quads contiguous) ----------------
__global__ void k_pack_whh(const float* __restrict__ whh, float* __restrict__ wp) {
    __shared__ float t[64][65];
    int j0 = blockIdx.x * 64, k0 = blockIdx.y * 64;
    // load 64(j) x 64(k) tile, coalesced along k
    for (int idx = threadIdx.x; idx < 64 * 16; idx += 256) {
        int jj = idx >> 4, kq = idx & 15;
        int j = j0 + jj, k = k0 + kq * 4;
        if (j < G4 && k < HH) {
            float4 v = *(const float4*)(whh + (size_t)j * HH + k);
            t[jj][kq * 4 + 0] = v.x; t[jj][kq * 4 + 1] = v.y;
            t[jj][kq * 4 + 2] = v.z; t[jj][kq * 4 + 3] = v.w;
        }
    }
    __syncthreads();
    // write: float4 per (k-quad, j), coalesced along j
    float4* W4 = (float4*)wp;
    for (int idx = threadIdx.x; idx < 16 * 64; idx += 256) {
        int kq = idx >> 6, jj = idx & 63;
        int j = j0 + jj, k = k0 + kq * 4;
        if (j < G4 && k < HH) {
            float4 v;
            v.x = t[jj][kq * 4 + 0]; v.y = t[jj][kq * 4 + 1];
            v.z = t[jj][kq * 4 + 2]; v.w = t[jj][kq * 4 + 3];
            W4[(size_t)(k >> 2) * G4 + j] = v;
        }
    }
}

// ---------------- sort along parts axis ----------------
__global__ void k_sort(const float* __restrict__ x, float* __restrict__ seq) {
    int tid = blockIdx.x * 256 + threadIdx.x;
    if (tid >= BB * EE) return;
    int b = tid / EE, e = tid % EE;
    float v[NN];
    for (int n = 0; n < NN; n++) v[n] = x[(b * NN + n) * EE + e];
    for (int i = 1; i < NN; i++) {
        float key = v[i];
        int j = i - 1;
        while (j >= 0 && v[j] > key) { v[j + 1] = v[j]; j--; }
        v[j + 1] = key;
    }
    for (int n = 0; n < NN; n++) seq[(n * BB + b) * EE + e] = v[n];
}

// ---------------- pairs gather: pairs[r][0:256]=x[b][ii[p]], [256:512]=x[b][jj[p]] ----------------
__global__ void k_pairs(const float* __restrict__ x, const int* __restrict__ iijj,
                        float* __restrict__ pairs) {
    int idx = blockIdx.x * 256 + threadIdx.x; // quad index
    int r = idx >> 7;
    if (r >= ROWS) return;
    int q = idx & 127, k = q << 2;
    int b = r / PP, p = r - b * PP;
    int part = (k < EE) ? iijj[p] : iijj[PP + p];
    float4 v = *(const float4*)(x + (size_t)(b * NN + part) * EE + (k & (EE - 1)));
    *(float4*)(pairs + (size_t)r * QIN + k) = v;
}

// ---------------- tiled GEMM: C[M][N] = act(A[M][K] @ Bw[K][N] + bias + pb) ----------------
// 64x64 tile, BK=16, 256 threads, 4x4 micro-tile. M % 64 == 0, K % 4 == 0, N % 4 == 0.
__global__ void k_gemm(const float* __restrict__ A, const float* __restrict__ Bw,
                       const float* __restrict__ bias, const float* __restrict__ pbm,
                       float* __restrict__ C, int M, int K, int N, int relu) {
    __shared__ __align__(16) float As[16][68];
    __shared__ __align__(16) float Bs[16][64];
    int tid = threadIdx.x;
    int m0 = blockIdx.y * 64, n0 = blockIdx.x * 64;
    int am = tid >> 2, ak4 = (tid & 3) << 2;
    int bk = tid >> 4, bn4 = (tid & 15) << 2;
    int tm = tid >> 4, tn = tid & 15;
    float acc[4][4] = {{0.f}};
    for (int k0 = 0; k0 < K; k0 += 16) {
        float4 av = {0.f, 0.f, 0.f, 0.f};
        if (k0 + ak4 < K) av = *(const float4*)(A + (size_t)(m0 + am) * K + k0 + ak4);
        float4 bv = {0.f, 0.f, 0.f, 0.f};
        if (k0 + bk < K && n0 + bn4 < N) bv = *(const float4*)(Bw + (size_t)(k0 + bk) * N + n0 + bn4);
        __syncthreads();
        As[ak4 + 0][am] = av.x; As[ak4 + 1][am] = av.y;
        As[ak4 + 2][am] = av.z; As[ak4 + 3][am] = av.w;
        *(float4*)&Bs[bk][bn4] = bv;
        __syncthreads();
#pragma unroll
        for (int kk = 0; kk < 16; kk++) {
            float4 a = *(const float4*)&As[kk][tm << 2];
            float4 b = *(const float4*)&Bs[kk][tn << 2];
            acc[0][0] += a.x * b.x; acc[0][1] += a.x * b.y; acc[0][2] += a.x * b.z; acc[0][3] += a.x * b.w;
            acc[1][0] += a.y * b.x; acc[1][1] += a.y * b.y; acc[1][2] += a.y * b.z; acc[1][3] += a.y * b.w;
            acc[2][0] += a.z * b.x; acc[2][1] += a.z * b.y; acc[2][2] += a.z * b.z; acc[2][3] += a.z * b.w;
            acc[3][0] += a.w * b.x; acc[3][1] += a.w * b.y; acc[3][2] += a.w * b.z; acc[3][3] += a.w * b.w;
        }
    }
    int col0 = n0 + (tn << 2);
    if (col0 >= N) return;
    float4 bb0 = {0.f, 0.f, 0.f, 0.f};
    if (bias) bb0 = *(const float4*)(bias + col0);
#pragma unroll
    for (int i = 0; i < 4; i++) {
        int row = m0 + (tm << 2) + i;
        float4 pv = {0.f, 0.f, 0.f, 0.f};
        if (pbm) pv = *(const float4*)(pbm + (size_t)(row / PP) * N + col0);
        float4 r;
        r.x = acc[i][0] + bb0.x + pv.x;
        r.y = acc[i][1] + bb0.y + pv.y;
        r.z = acc[i][2] + bb0.z + pv.z;
        r.w = acc[i][3] + bb0.w + pv.w;
        if (relu) {
            r.x = fmaxf(r.x, 0.f); r.y = fmaxf(r.y, 0.f);
            r.z = fmaxf(r.z, 0.f); r.w = fmaxf(r.w, 0.f);
        }
        *(float4*)(C + (size_t)row * N + col0) = r;
    }
}

// ---------------- LSTM recurrent GEMM: all 32 batches per block, weights read once ----------------
// grid (48, KS2), block 128. wp packed [k/4][6000] float4.
__global__ void k_lstm_gemm2(const float* __restrict__ h, const float* __restrict__ wp,
                             float* __restrict__ gpart) {
    __shared__ __align__(16) float hs[32][KCH2];
    int tid = threadIdx.x;
    int j = blockIdx.x * 128 + tid;
    int k0 = blockIdx.y * KCH2;
    int klen = min(KCH2, HH - k0);
    int quads = klen >> 2;
    for (int idx = tid; idx < 32 * quads; idx += 128) {
        int bb = idx / quads, kq = idx - bb * quads;
        float4 v = *(const float4*)(h + (size_t)bb * HH + k0 + (kq << 2));
        *(float4*)&hs[bb][kq << 2] = v;
    }
    __syncthreads();
    if (j >= G4) return;
    const float4* W4 = (const float4*)wp;
    size_t wbase = (size_t)(k0 >> 2) * G4 + j;
    float acc[32];
#pragma unroll
    for (int bb = 0; bb < 32; bb++) acc[bb] = 0.f;
    float4 wq = W4[wbase];
    int kq = 0;
    for (; kq + 1 < quads; kq++) {
        float4 wn = W4[wbase + (size_t)(kq + 1) * G4];
#pragma unroll
        for (int bb = 0; bb < 32; bb++) {
            float4 hq = *(const float4*)&hs[bb][kq << 2];
            acc[bb] += hq.x * wq.x + hq.y * wq.y + hq.z * wq.z + hq.w * wq.w;
        }
        wq = wn;
    }
#pragma unroll
    for (int bb = 0; bb < 32; bb++) {
        float4 hq = *(const float4*)&hs[bb][kq << 2];
        acc[bb] += hq.x * wq.x + hq.y * wq.y + hq.z * wq.z + hq.w * wq.w;
    }
#pragma unroll
    for (int bb = 0; bb < 32; bb++)
        gpart[(size_t)(blockIdx.y * BB + bb) * G4 + j] = acc[bb];
}

// ---------------- LSTM gate nonlinearity + state update ----------------
__global__ void k_lstm_gate(const float* __restrict__ xg_n, const float* __restrict__ gpart,
                            float* __restrict__ c, float* __restrict__ h_out) {
    int idx = blockIdx.x * 256 + threadIdx.x;
    if (idx >= BB * HH) return;
    int b = idx / HH, jh = idx - b * HH;
    float g4[4];
#pragma unroll
    for (int g = 0; g < 4; g++) {
        float v = xg_n[(size_t)b * G4 + g * HH + jh];
#pragma unroll
        for (int s = 0; s < KS2; s++) v += gpart[(size_t)(s * BB + b) * G4 + g * HH + jh];
        g4[g] = v;
    }
    float ci = c[idx];
    float cn = sigm(g4[1]) * ci + sigm(g4[0]) * tanhf(g4[2]);
    c[idx] = cn;
    h_out[idx] = sigm(g4[3]) * tanhf(cn);
}

// ---------------- plan-side e1 bias ----------------
__global__ void k_pb(const float* __restrict__ plan, const float* __restrict__ e1at,
                     const float* __restrict__ e1b, float* __restrict__ pb) {
    __shared__ float ps[HH];
    int b = blockIdx.y;
    for (int idx = threadIdx.x; idx < HH; idx += 256) ps[idx] = plan[b * HH + idx];
    __syncthreads();
    int o = blockIdx.x * 256 + threadIdx.x;
    if (o >= EV1) return;
    float acc = e1b[o];
    for (int k = 0; k < HH; k++) acc += ps[k] * e1at[(size_t)k * EV1 + o];
    pb[b * EV1 + o] = acc;
}

// ---------------- fused e3 + e4 tail ----------------
__global__ void k_e34(const float* __restrict__ e2out, const float* __restrict__ e3t,
                      const float* __restrict__ e3b, const float* __restrict__ e4w,
                      const float* __restrict__ e4b, float* __restrict__ out) {
    __shared__ float wt[EV2 * EV3];
    for (int idx = threadIdx.x; idx < EV2 * EV3; idx += 256) wt[idx] = e3t[idx];
    __syncthreads();
    int r = blockIdx.x * 256 + threadIdx.x;
    if (r >= ROWS) return;
    float h3[EV3];
#pragma unroll
    for (int o3 = 0; o3 < EV3; o3++) h3[o3] = e3b[o3];
    for (int k = 0; k < EV2; k++) {
        float v = e2out[(size_t)r * EV2 + k];
#pragma unroll
        for (int o3 = 0; o3 < EV3; o3++) h3[o3] += v * wt[k * EV3 + o3];
    }
    float acc = e4b[0];
#pragma unroll
    for (int o3 = 0; o3 < EV3; o3++) acc += fmaxf(h3[o3], 0.f) * e4w[o3];
    out[r] = fmaxf(acc, 0.f);
}

// ---------------- host launch ----------------
extern "C" void kernel_launch(void* const* d_in, const int* in_sizes, int n_in,
                              void* d_out, int out_size, void* d_ws, size_t ws_size,
                              hipStream_t stream) {
    const float* x    = (const float*)d_in[0];
    const float* w_ih = (const float*)d_in[1];
    const float* w_hh = (const float*)d_in[2];
    const float* b_ih = (const float*)d_in[3];
    const float* b_hh = (const float*)d_in[4];
    const float* q1_w = (const float*)d_in[5];
    const float* q1_b = (const float*)d_in[6];
    const float* q2_w = (const float*)d_in[7];
    const float* q2_b = (const float*)d_in[8];
    const float* e1_w = (const float*)d_in[9];
    const float* e1_b = (const float*)d_in[10];
    const float* e2_w = (const float*)d_in[11];
    const float* e2_b = (const float*)d_in[12];
    const float* e3_w = (const float*)d_in[13];
    const float* e3_b = (const float*)d_in[14];
    const float* e4_w = (const float*)d_in[15];
    const float* e4_b = (const float*)d_in[16];
    float* out = (float*)d_out;
    float* ws = (float*)d_ws;

    // workspace layout (float offsets)
    size_t off = 0;
    float* seq    = ws + off; off += (size_t)NN * BB * EE;          // 262,144
    size_t regionA = off;
    float* wp     = ws + off; off += (size_t)375 * G4 * 4;          // 9,000,000 (packed w_hh^T)
    float* xg     = ws + off; off += (size_t)NN * BB * G4;          // 6,144,000
    float* gpart  = ws + off; off += (size_t)KS2 * BB * G4;         // 1,536,000
    // regionA spans wp+xg+gpart = 16,680,000 floats; aliases pairs (8,126,464)
    // and later e1out (15,872,000) — both live only after the LSTM is done.
    float* pairs  = ws + regionA;
    float* e1out  = ws + regionA;
    float* h0     = ws + off; off += BB * HH;
    float* h1     = ws + off; off += BB * HH;
    float* cst    = ws + off; off += BB * HH;
    float* wih_t  = ws + off; off += (size_t)EE * G4;               // 1,536,000
    float* q1t    = ws + off; off += (size_t)QIN * Q1O;
    float* q1beff = ws + off; off += 1024;
    float* bsum   = ws + off; off += G4;
    float* q2t    = ws + off; off += (size_t)Q1O * QO;
    float* e1at   = ws + off; off += (size_t)HH * EV1;
    float* e1bt   = ws + off; off += (size_t)QO * EV1;
    float* e2t    = ws + off; off += (size_t)EV1 * EV2;
    float* e3t    = ws + off; off += 1024;
    float* pb     = ws + off; off += BB * EV1;
    float* q1out  = ws + off; off += (size_t)ROWS * Q1O;
    float* q2out  = ws + off; off += (size_t)ROWS * QO;
    float* e2out  = ws + off; off += (size_t)ROWS * EV2;
    int*   iijj   = (int*)(ws + off); off += 1024;

    dim3 tb(32, 8);

    // init
    k_iijj<<<1, 512, 0, stream>>>(iijj);
    k_q1beff<<<3, 256, 0, stream>>>(q1_w, q1_b, q1beff);
    k_addb<<<24, 256, 0, stream>>>(b_ih, b_hh, bsum, G4);
    k_zero<<<188, 256, 0, stream>>>(h0, BB * HH);
    k_zero<<<188, 256, 0, stream>>>(cst, BB * HH);

    // weight transforms
    k_transpose<<<dim3(8, 188), tb, 0, stream>>>(w_ih, wih_t, G4, EE, 0, EE);
    k_pack_whh<<<dim3(94, 24), 256, 0, stream>>>(w_hh, wp);
    k_transpose<<<dim3(16, 19), tb, 0, stream>>>(q1_w, q1t, Q1O, QIN, 0, QIN);
    k_transpose<<<dim3(19, 10), tb, 0, stream>>>(q2_w, q2t, QO, Q1O, 0, Q1O);
    k_transpose<<<dim3(47, 32), tb, 0, stream>>>(e1_w, e1at, EV1, HH + QO, 0, HH);
    k_transpose<<<dim3(10, 32), tb, 0, stream>>>(e1_w, e1bt, EV1, HH + QO, HH, QO);
    k_transpose<<<dim3(32, 4), tb, 0, stream>>>(e2_w, e2t, EV2, EV1, 0, EV1);
    k_transpose<<<dim3(4, 1), tb, 0, stream>>>(e3_w, e3t, EV3, EV2, 0, EV2);

    // sort + x-side gates (xg = seq @ wih_t + bsum), M=1024 K=256 N=6000
    k_sort<<<32, 256, 0, stream>>>(x, seq);
    k_gemm<<<dim3(94, 16), 256, 0, stream>>>(seq, wih_t, bsum, nullptr, xg, 1024, EE, G4, 0);

    // LSTM: 32 sequential steps
    float* hbuf[2] = {h0, h1};
    for (int n = 0; n < NN; n++) {
        k_lstm_gemm2<<<dim3(48, KS2), 128, 0, stream>>>(hbuf[n & 1], wp, gpart);
        k_lstm_gate<<<188, 256, 0, stream>>>(xg + (size_t)n * BB * G4, gpart, cst, hbuf[(n + 1) & 1]);
    }
    float* plan = hbuf[0]; // after 32 steps

    // evaluator plan-side bias (includes e1_b)
    k_pb<<<dim3(4, BB), 256, 0, stream>>>(plan, e1at, e1_b, pb);

    // pair MLP (pairs gather overwrites dead wp/xg region — must come after LSTM)
    k_pairs<<<7936, 256, 0, stream>>>(x, iijj, pairs);
    k_gemm<<<dim3(10, 248), 256, 0, stream>>>(pairs, q1t, q1beff, nullptr, q1out, ROWS, QIN, Q1O, 1);
    k_gemm<<<dim3(5, 248), 256, 0, stream>>>(q1out, q2t, q2_b, nullptr, q2out, ROWS, Q1O, QO, 1);
    k_gemm<<<dim3(16, 248), 256, 0, stream>>>(q2out, e1bt, nullptr, pb, e1out, ROWS, QO, EV1, 1);
    k_gemm<<<dim3(2, 248), 256, 0, stream>>>(e1out, e2t, e2_b, nullptr, e2out, ROWS, EV1, EV2, 1);
    k_e34<<<62, 256, 0, stream>>>(e2out, e3t, e3_b, e4_w, e4_b, out);
}

// Round 3
// 1946.190 us; speedup vs baseline: 4.9104x; 4.9104x over previous
//
#include <hip/hip_runtime.h>
#include <math.h>

// Problem dims
#define BB 32
#define NN 32
#define EE 256
#define HH 1500
#define G4 6000      // 4*HH
#define QIN 512
#define Q1O 600
#define QO 300
#define EV1 1000
#define EV2 100
#define EV3 10
#define PP 496       // N*(N-1)/2
#define ROWS (BB*PP) // 15872
#define KS3 16       // lstm k-split
#define KCH3 96      // k-chunk (last split = 60)
#define BH (BB*HH)   // 48000

__device__ __forceinline__ float sigm(float x) { return 1.f / (1.f + expf(-x)); }

// ---------------- init helpers ----------------
__global__ void k_zero(float* a, int n) {
    int i = blockIdx.x * 256 + threadIdx.x;
    if (i < n) a[i] = 0.f;
}

__global__ void k_iijj(int* iijj) {
    int p = threadIdx.x;
    if (p >= PP) return;
    int i = 0, p0 = 0;
    while (p >= p0 + (NN - 1 - i)) { p0 += NN - 1 - i; i++; }
    iijj[p] = i;
    iijj[PP + p] = i + 1 + (p - p0);
}

// q1 effective bias: q1_b[o] + sum over odd k of q1_w[o][k]  (PE at pos 0)
__global__ void k_q1beff(const float* q1w, const float* q1b, float* beff) {
    int o = blockIdx.x * 256 + threadIdx.x;
    if (o >= Q1O) return;
    float a = q1b[o];
    for (int k = 1; k < QIN; k += 2) a += q1w[o * QIN + k];
    beff[o] = a;
}

__global__ void k_addb(const float* a, const float* b, float* c, int n) {
    int i = blockIdx.x * 256 + threadIdx.x;
    if (i < n) c[i] = a[i] + b[i];
}

// ---------------- transpose (sub-range of columns) ----------------
// src[R][C], take columns [c0, c0+csub) -> dst[csub][R]
__global__ void k_transpose(const float* __restrict__ src, float* __restrict__ dst,
                            int R, int C, int c0, int csub) {
    __shared__ float tile[32][33];
    int cb = blockIdx.x * 32, rb = blockIdx.y * 32;
    for (int dy = threadIdx.y; dy < 32; dy += 8) {
        int r = rb + dy, c = cb + threadIdx.x;
        if (r < R && c < csub) tile[dy][threadIdx.x] = src[(size_t)r * C + c0 + c];
    }
    __syncthreads();
    for (int dy = threadIdx.y; dy < 32; dy += 8) {
        int c = cb + dy, r = rb + threadIdx.x;
        if (c < csub && r < R) dst[(size_t)c * R + r] = tile[threadIdx.x][dy];
    }
}

// ---------------- pack w_hh -> wp[k/4][6000] of float4 (w^T, k-quads contiguous) ----------------
__global__ void k_pack_whh(const float* __restrict__ whh, float* __restrict__ wp) {
    __shared__ float t[64][65];
    int j0 = blockIdx.x * 64, k0 = blockIdx.y * 64;
    for (int idx = threadIdx.x; idx < 64 * 16; idx += 256) {
        int jj = idx >> 4, kq = idx & 15;
        int j = j0 + jj, k = k0 + kq * 4;
        if (j < G4 && k < HH) {
            float4 v = *(const float4*)(whh + (size_t)j * HH + k);
            t[jj][kq * 4 + 0] = v.x; t[jj][kq * 4 + 1] = v.y;
            t[jj][kq * 4 + 2] = v.z; t[jj][kq * 4 + 3] = v.w;
        }
    }
    __syncthreads();
    float4* W4 = (float4*)wp;
    for (int idx = threadIdx.x; idx < 16 * 64; idx += 256) {
        int kq = idx >> 6, jj = idx & 63;
        int j = j0 + jj, k = k0 + kq * 4;
        if (j < G4 && k < HH) {
            float4 v;
            v.x = t[jj][kq * 4 + 0]; v.y = t[jj][kq * 4 + 1];
            v.z = t[jj][kq * 4 + 2]; v.w = t[jj][kq * 4 + 3];
            W4[(size_t)(k >> 2) * G4 + j] = v;
        }
    }
}

// ---------------- sort along parts axis ----------------
__global__ void k_sort(const float* __restrict__ x, float* __restrict__ seq) {
    int tid = blockIdx.x * 256 + threadIdx.x;
    if (tid >= BB * EE) return;
    int b = tid / EE, e = tid % EE;
    float v[NN];
    for (int n = 0; n < NN; n++) v[n] = x[(b * NN + n) * EE + e];
    for (int i = 1; i < NN; i++) {
        float key = v[i];
        int j = i - 1;
        while (j >= 0 && v[j] > key) { v[j + 1] = v[j]; j--; }
        v[j + 1] = key;
    }
    for (int n = 0; n < NN; n++) seq[(n * BB + b) * EE + e] = v[n];
}

// ---------------- transpose xg[(n*32+b)][j] -> xgT[n][j][b] ----------------
__global__ void k_xgt(const float* __restrict__ xg, float* __restrict__ xgT) {
    __shared__ float t[32][33];
    int n = blockIdx.z;
    int j0 = blockIdx.x * 32;
    for (int dy = threadIdx.y; dy < 32; dy += 8) {
        int j = j0 + threadIdx.x;
        if (j < G4) t[dy][threadIdx.x] = xg[(size_t)(n * 32 + dy) * G4 + j];
    }
    __syncthreads();
    for (int dy = threadIdx.y; dy < 32; dy += 8) {
        int j = j0 + dy;
        if (j < G4) xgT[(size_t)n * (G4 * BB) + (size_t)j * BB + threadIdx.x] = t[threadIdx.x][dy];
    }
}

// ---------------- pairs gather ----------------
__global__ void k_pairs(const float* __restrict__ x, const int* __restrict__ iijj,
                        float* __restrict__ pairs) {
    int idx = blockIdx.x * 256 + threadIdx.x; // quad index
    int r = idx >> 7;
    if (r >= ROWS) return;
    int q = idx & 127, k = q << 2;
    int b = r / PP, p = r - b * PP;
    int part = (k < EE) ? iijj[p] : iijj[PP + p];
    float4 v = *(const float4*)(x + (size_t)(b * NN + part) * EE + (k & (EE - 1)));
    *(float4*)(pairs + (size_t)r * QIN + k) = v;
}

// ---------------- tiled GEMM: C[M][N] = act(A[M][K] @ Bw[K][N] + bias + pb) ----------------
// 64x64 tile, BK=16, 256 threads, 4x4 micro-tile. M % 64 == 0, K % 4 == 0, N % 4 == 0.
__global__ void k_gemm(const float* __restrict__ A, const float* __restrict__ Bw,
                       const float* __restrict__ bias, const float* __restrict__ pbm,
                       float* __restrict__ C, int M, int K, int N, int relu) {
    __shared__ __align__(16) float As[16][68];
    __shared__ __align__(16) float Bs[16][64];
    int tid = threadIdx.x;
    int m0 = blockIdx.y * 64, n0 = blockIdx.x * 64;
    int am = tid >> 2, ak4 = (tid & 3) << 2;
    int bk = tid >> 4, bn4 = (tid & 15) << 2;
    int tm = tid >> 4, tn = tid & 15;
    float acc[4][4] = {{0.f}};
    for (int k0 = 0; k0 < K; k0 += 16) {
        float4 av = {0.f, 0.f, 0.f, 0.f};
        if (k0 + ak4 < K) av = *(const float4*)(A + (size_t)(m0 + am) * K + k0 + ak4);
        float4 bv = {0.f, 0.f, 0.f, 0.f};
        if (k0 + bk < K && n0 + bn4 < N) bv = *(const float4*)(Bw + (size_t)(k0 + bk) * N + n0 + bn4);
        __syncthreads();
        As[ak4 + 0][am] = av.x; As[ak4 + 1][am] = av.y;
        As[ak4 + 2][am] = av.z; As[ak4 + 3][am] = av.w;
        *(float4*)&Bs[bk][bn4] = bv;
        __syncthreads();
#pragma unroll
        for (int kk = 0; kk < 16; kk++) {
            float4 a = *(const float4*)&As[kk][tm << 2];
            float4 b = *(const float4*)&Bs[kk][tn << 2];
            acc[0][0] += a.x * b.x; acc[0][1] += a.x * b.y; acc[0][2] += a.x * b.z; acc[0][3] += a.x * b.w;
            acc[1][0] += a.y * b.x; acc[1][1] += a.y * b.y; acc[1][2] += a.y * b.z; acc[1][3] += a.y * b.w;
            acc[2][0] += a.z * b.x; acc[2][1] += a.z * b.y; acc[2][2] += a.z * b.z; acc[2][3] += a.z * b.w;
            acc[3][0] += a.w * b.x; acc[3][1] += a.w * b.y; acc[3][2] += a.w * b.z; acc[3][3] += a.w * b.w;
        }
    }
    int col0 = n0 + (tn << 2);
    if (col0 >= N) return;
    float4 bb0 = {0.f, 0.f, 0.f, 0.f};
    if (bias) bb0 = *(const float4*)(bias + col0);
#pragma unroll
    for (int i = 0; i < 4; i++) {
        int row = m0 + (tm << 2) + i;
        float4 pv = {0.f, 0.f, 0.f, 0.f};
        if (pbm) pv = *(const float4*)(pbm + (size_t)(row / PP) * N + col0);
        float4 r;
        r.x = acc[i][0] + bb0.x + pv.x;
        r.y = acc[i][1] + bb0.y + pv.y;
        r.z = acc[i][2] + bb0.z + pv.z;
        r.w = acc[i][3] + bb0.w + pv.w;
        if (relu) {
            r.x = fmaxf(r.x, 0.f); r.y = fmaxf(r.y, 0.f);
            r.z = fmaxf(r.z, 0.f); r.w = fmaxf(r.w, 0.f);
        }
        *(float4*)(C + (size_t)row * N + col0) = r;
    }
}

// ---------------- LSTM recurrent GEMM, scalar-broadcast h ----------------
// ht[k][b] (transposed h). wp packed [k/4][6000] float4.
// grid (47, KS3), block 128; each thread: one j, acc over 32 batches.
// h reads are wave-uniform -> s_load; weights are per-lane dwordx4.
__global__ __launch_bounds__(128, 1)
void k_lstm_gemm3(const float* __restrict__ ht, const float* __restrict__ wp,
                  float* __restrict__ gpartT) {
    int j = blockIdx.x * 128 + threadIdx.x;
    if (j >= G4) return;
    int s = blockIdx.y;
    int k0 = s * KCH3;
    int klen = min(KCH3, HH - k0);
    int quads = klen >> 2;
    const float4* W4 = (const float4*)wp;
    size_t wbase = (size_t)(k0 >> 2) * G4 + j;
    float acc[BB];
#pragma unroll
    for (int b = 0; b < BB; b++) acc[b] = 0.f;
    float4 wq = W4[wbase];
    for (int kq = 0; kq < quads; kq++) {
        float4 wn;
        if (kq + 1 < quads) wn = W4[wbase + (size_t)(kq + 1) * G4];
        const float* hp = ht + (size_t)(k0 + (kq << 2)) * BB;  // uniform -> s_load
#pragma unroll
        for (int b = 0; b < BB; b++)
            acc[b] += wq.x * hp[b] + wq.y * hp[BB + b] + wq.z * hp[2 * BB + b] + wq.w * hp[3 * BB + b];
        wq = wn;
    }
    // contiguous 128B store per thread: gpartT[s][j][0:32]
    float* dst = gpartT + ((size_t)s * G4 + j) * BB;
#pragma unroll
    for (int q = 0; q < BB / 4; q++) {
        float4 v;
        v.x = acc[q * 4 + 0]; v.y = acc[q * 4 + 1];
        v.z = acc[q * 4 + 2]; v.w = acc[q * 4 + 3];
        *(float4*)(dst + q * 4) = v;
    }
}

// ---------------- LSTM gate nonlinearity + state update (transposed layout) ----------------
// t = jh*32 + b; xgT_n[g*48000 + t]; gpartT[s*192000 + g*48000 + t]
__global__ void k_lstm_gate3(const float* __restrict__ xgT_n, const float* __restrict__ gpartT,
                             float* __restrict__ ct, float* __restrict__ ht) {
    int t = blockIdx.x * 256 + threadIdx.x;
    if (t >= BH) return;
    float g4[4];
#pragma unroll
    for (int g = 0; g < 4; g++) {
        float v = xgT_n[g * BH + t];
#pragma unroll
        for (int s = 0; s < KS3; s++) v += gpartT[(size_t)s * (G4 * BB) + g * BH + t];
        g4[g] = v;
    }
    float ci = ct[t];
    float cn = sigm(g4[1]) * ci + sigm(g4[0]) * tanhf(g4[2]);
    ct[t] = cn;
    ht[t] = sigm(g4[3]) * tanhf(cn);
}

// ---------------- plan-side e1 bias (plan in transposed ht layout) ----------------
__global__ void k_pb(const float* __restrict__ ht, const float* __restrict__ e1at,
                     const float* __restrict__ e1b, float* __restrict__ pb) {
    __shared__ float ps[HH];
    int b = blockIdx.y;
    for (int idx = threadIdx.x; idx < HH; idx += 256) ps[idx] = ht[(size_t)idx * BB + b];
    __syncthreads();
    int o = blockIdx.x * 256 + threadIdx.x;
    if (o >= EV1) return;
    float acc = e1b[o];
    for (int k = 0; k < HH; k++) acc += ps[k] * e1at[(size_t)k * EV1 + o];
    pb[b * EV1 + o] = acc;
}

// ---------------- fused e3 + e4 tail ----------------
__global__ void k_e34(const float* __restrict__ e2out, const float* __restrict__ e3t,
                      const float* __restrict__ e3b, const float* __restrict__ e4w,
                      const float* __restrict__ e4b, float* __restrict__ out) {
    __shared__ float wt[EV2 * EV3];
    for (int idx = threadIdx.x; idx < EV2 * EV3; idx += 256) wt[idx] = e3t[idx];
    __syncthreads();
    int r = blockIdx.x * 256 + threadIdx.x;
    if (r >= ROWS) return;
    float h3[EV3];
#pragma unroll
    for (int o3 = 0; o3 < EV3; o3++) h3[o3] = e3b[o3];
    for (int k = 0; k < EV2; k++) {
        float v = e2out[(size_t)r * EV2 + k];
#pragma unroll
        for (int o3 = 0; o3 < EV3; o3++) h3[o3] += v * wt[k * EV3 + o3];
    }
    float acc = e4b[0];
#pragma unroll
    for (int o3 = 0; o3 < EV3; o3++) acc += fmaxf(h3[o3], 0.f) * e4w[o3];
    out[r] = fmaxf(acc, 0.f);
}

// ---------------- host launch ----------------
extern "C" void kernel_launch(void* const* d_in, const int* in_sizes, int n_in,
                              void* d_out, int out_size, void* d_ws, size_t ws_size,
                              hipStream_t stream) {
    const float* x    = (const float*)d_in[0];
    const float* w_ih = (const float*)d_in[1];
    const float* w_hh = (const float*)d_in[2];
    const float* b_ih = (const float*)d_in[3];
    const float* b_hh = (const float*)d_in[4];
    const float* q1_w = (const float*)d_in[5];
    const float* q1_b = (const float*)d_in[6];
    const float* q2_w = (const float*)d_in[7];
    const float* q2_b = (const float*)d_in[8];
    const float* e1_w = (const float*)d_in[9];
    const float* e1_b = (const float*)d_in[10];
    const float* e2_w = (const float*)d_in[11];
    const float* e2_b = (const float*)d_in[12];
    const float* e3_w = (const float*)d_in[13];
    const float* e3_b = (const float*)d_in[14];
    const float* e4_w = (const float*)d_in[15];
    const float* e4_b = (const float*)d_in[16];
    float* out = (float*)d_out;
    float* ws = (float*)d_ws;

    // workspace layout (float offsets)
    size_t off = 0;
    float* seq    = ws + off; off += (size_t)NN * BB * EE;          // 262,144
    size_t regionA = off; off += 17700000;
    // regionA phases:
    //  pre-LSTM : wp [0,9M) | xg [9M,15.14M)
    //  LSTM     : wp [0,9M) | gpartT [9M,12.07M)   (xg dead after xgT built)
    //  pairs/q1 : pairs [0,8.13M) | q1out [8.13M,17.65M)
    //  e1       : e1out [0,15.87M)                 (pairs,q1out dead)
    float* wp     = ws + regionA;                                   // 9,000,000
    float* xg     = ws + regionA + 9000000;                         // 6,144,000
    float* gpartT = ws + regionA + 9000000;                         // 3,072,000 (aliases dead xg)
    float* pairs  = ws + regionA;                                   // 8,126,464
    float* q1out  = ws + regionA + 8130000;                         // 9,523,200
    float* e1out  = ws + regionA;                                   // 15,872,000
    float* xgT    = ws + off; off += (size_t)NN * G4 * BB;          // 6,144,000
    float* ht     = ws + off; off += BH;
    float* ct     = ws + off; off += BH;
    float* wih_t  = ws + off; off += (size_t)EE * G4;               // 1,536,000
    float* q1t    = ws + off; off += (size_t)QIN * Q1O;
    float* q1beff = ws + off; off += 1024;
    float* bsum   = ws + off; off += G4;
    float* q2t    = ws + off; off += (size_t)Q1O * QO;
    float* e1at   = ws + off; off += (size_t)HH * EV1;
    float* e1bt   = ws + off; off += (size_t)QO * EV1;
    float* e2t    = ws + off; off += (size_t)EV1 * EV2;
    float* e3t    = ws + off; off += 1024;
    float* pb     = ws + off; off += BB * EV1;
    float* q2out  = ws + off; off += (size_t)ROWS * QO;
    float* e2out  = ws + off; off += (size_t)ROWS * EV2;
    int*   iijj   = (int*)(ws + off); off += 1024;

    dim3 tb(32, 8);

    // init
    k_iijj<<<1, 512, 0, stream>>>(iijj);
    k_q1beff<<<3, 256, 0, stream>>>(q1_w, q1_b, q1beff);
    k_addb<<<24, 256, 0, stream>>>(b_ih, b_hh, bsum, G4);
    k_zero<<<188, 256, 0, stream>>>(ht, BH);
    k_zero<<<188, 256, 0, stream>>>(ct, BH);

    // weight transforms
    k_transpose<<<dim3(8, 188), tb, 0, stream>>>(w_ih, wih_t, G4, EE, 0, EE);
    k_pack_whh<<<dim3(94, 24), 256, 0, stream>>>(w_hh, wp);
    k_transpose<<<dim3(16, 19), tb, 0, stream>>>(q1_w, q1t, Q1O, QIN, 0, QIN);
    k_transpose<<<dim3(19, 10), tb, 0, stream>>>(q2_w, q2t, QO, Q1O, 0, Q1O);
    k_transpose<<<dim3(47, 32), tb, 0, stream>>>(e1_w, e1at, EV1, HH + QO, 0, HH);
    k_transpose<<<dim3(10, 32), tb, 0, stream>>>(e1_w, e1bt, EV1, HH + QO, HH, QO);
    k_transpose<<<dim3(32, 4), tb, 0, stream>>>(e2_w, e2t, EV2, EV1, 0, EV1);
    k_transpose<<<dim3(4, 1), tb, 0, stream>>>(e3_w, e3t, EV3, EV2, 0, EV2);

    // sort + x-side gates (xg = seq @ wih_t + bsum), then transpose to [n][j][b]
    k_sort<<<32, 256, 0, stream>>>(x, seq);
    k_gemm<<<dim3(94, 16), 256, 0, stream>>>(seq, wih_t, bsum, nullptr, xg, 1024, EE, G4, 0);
    k_xgt<<<dim3(188, 1, 32), tb, 0, stream>>>(xg, xgT);

    // LSTM: 32 sequential steps (gpartT overwrites dead xg region)
    for (int n = 0; n < NN; n++) {
        k_lstm_gemm3<<<dim3(47, KS3), 128, 0, stream>>>(ht, wp, gpartT);
        k_lstm_gate3<<<188, 256, 0, stream>>>(xgT + (size_t)n * (G4 * BB), gpartT, ct, ht);
    }

    // evaluator plan-side bias (includes e1_b)
    k_pb<<<dim3(4, BB), 256, 0, stream>>>(ht, e1at, e1_b, pb);

    // pair MLP (pairs gather overwrites dead wp region — must come after LSTM)
    k_pairs<<<7936, 256, 0, stream>>>(x, iijj, pairs);
    k_gemm<<<dim3(10, 248), 256, 0, stream>>>(pairs, q1t, q1beff, nullptr, q1out, ROWS, QIN, Q1O, 1);
    k_gemm<<<dim3(5, 248), 256, 0, stream>>>(q1out, q2t, q2_b, nullptr, q2out, ROWS, Q1O, QO, 1);
    k_gemm<<<dim3(16, 248), 256, 0, stream>>>(q2out, e1bt, nullptr, pb, e1out, ROWS, QO, EV1, 1);
    k_gemm<<<dim3(2, 248), 256, 0, stream>>>(e1out, e2t, e2_b, nullptr, e2out, ROWS, EV1, EV2, 1);
    k_e34<<<62, 256, 0, stream>>>(e2out, e3t, e3_b, e4_w, e4_b, out);
}